// Round 5
// baseline (7155.817 us; speedup 1.0000x reference)
//
#include <hip/hip_runtime.h>
#include <hip/hip_cooperative_groups.h>
#include <math.h>

namespace cg = cooperative_groups;

#define B 128
#define S 20
#define H 512
#define E 512
#define V 10000
#define NG 2048   // 4*H (gate width)
#define HB 1024   // 2*H (state row width)

__device__ __forceinline__ float sigf(float x) { return 1.0f / (1.0f + expf(-x)); }

// dot-products of one weight column (LDS) against two A-rows (global), K=512
__device__ __forceinline__ void dotpair512(
    const float* __restrict__ wt, const float* __restrict__ a0,
    const float* __restrict__ a1, float& acc0, float& acc1)
{
  float s0e=0.f, s0o=0.f, s1e=0.f, s1o=0.f;
  #pragma unroll 8
  for (int k = 0; k < 512; k += 4) {
    float4 w4 = *(const float4*)(wt + k);
    float4 x0 = *(const float4*)(a0 + k);
    float4 x1 = *(const float4*)(a1 + k);
    s0e = fmaf(w4.x, x0.x, s0e); s0o = fmaf(w4.y, x0.y, s0o);
    s0e = fmaf(w4.z, x0.z, s0e); s0o = fmaf(w4.w, x0.w, s0o);
    s1e = fmaf(w4.x, x1.x, s1e); s1o = fmaf(w4.y, x1.y, s1o);
    s1e = fmaf(w4.z, x1.z, s1e); s1o = fmaf(w4.w, x1.w, s1o);
  }
  acc0 += s0e + s0o; acc1 += s1e + s1o;
}

// single-row K=512 dot (for att partials)
__device__ __forceinline__ float dot512(
    const float* __restrict__ wt, const float* __restrict__ a)
{
  float se=0.f, so=0.f, se2=0.f, so2=0.f;
  #pragma unroll 8
  for (int k = 0; k < 512; k += 8) {
    float4 w4 = *(const float4*)(wt + k);
    float4 x4 = *(const float4*)(a + k);
    float4 w5 = *(const float4*)(wt + k + 4);
    float4 x5 = *(const float4*)(a + k + 4);
    se  = fmaf(w4.x, x4.x, se );  so  = fmaf(w4.y, x4.y, so );
    se  = fmaf(w4.z, x4.z, se );  so  = fmaf(w4.w, x4.w, so );
    se2 = fmaf(w5.x, x5.x, se2);  so2 = fmaf(w5.y, x5.y, so2);
    se2 = fmaf(w5.z, x5.z, se2);  so2 = fmaf(w5.w, x5.w, so2);
  }
  return (se + so) + (se2 + so2);
}

// ---------------------------------------------------------------------------
// K1: X0G[t*B+b][n] = concat(baseimg[b], emb[tok[b][t]]) @ W0[0:1024,:] + b0
// M=2560, N=2048, K=1024.  (parallel, off critical path)
// ---------------------------------------------------------------------------
__global__ __launch_bounds__(256) void k_x0g(
    const int* __restrict__ tok, const float* __restrict__ base,
    const float* __restrict__ emb, const float* __restrict__ W0,
    const float* __restrict__ b0, float* __restrict__ X0G)
{
  __shared__ __align__(16) float As[8][128];
  __shared__ __align__(16) float Bs[8][128];
  const int tid = threadIdx.x;
  const int m0 = blockIdx.y * 128, n0 = blockIdx.x * 128;
  const int tx = tid & 15, ty = tid >> 4;

  const int rloc = tid >> 1;
  const int arow = m0 + rloc;
  const int ak4  = (tid & 1) * 4;
  const int t_ = arow >> 7, b_ = arow & 127;
  const int token = tok[b_ * S + t_];
  const float* arow_lo = base + (size_t)b_ * E;
  const float* arow_hi = emb + (size_t)token * E;

  const int bkk = tid >> 5;
  const int bc4 = (tid & 31) * 4;

  float acc[2][2][4][4];
  #pragma unroll
  for (int p=0;p<2;p++)
    #pragma unroll
    for (int q=0;q<2;q++)
      #pragma unroll
      for (int i=0;i<4;i++)
        #pragma unroll
        for (int j=0;j<4;j++) acc[p][q][i][j]=0.f;

  for (int kt = 0; kt < 1024/8; ++kt) {
    const int k = kt*8 + ak4;
    float4 av = (k < 512) ? *(const float4*)(arow_lo + k)
                          : *(const float4*)(arow_hi + (k - 512));
    float4 bv = *(const float4*)(W0 + (size_t)(kt*8 + bkk)*NG + n0 + bc4);
    __syncthreads();
    As[ak4+0][rloc] = av.x; As[ak4+1][rloc] = av.y;
    As[ak4+2][rloc] = av.z; As[ak4+3][rloc] = av.w;
    *(float4*)&Bs[bkk][bc4] = bv;
    __syncthreads();
    #pragma unroll
    for (int kk=0; kk<8; ++kk) {
      float a[2][4], b[2][4];
      *(float4*)a[0] = *(const float4*)&As[kk][ty*4];
      *(float4*)a[1] = *(const float4*)&As[kk][64 + ty*4];
      *(float4*)b[0] = *(const float4*)&Bs[kk][tx*4];
      *(float4*)b[1] = *(const float4*)&Bs[kk][64 + tx*4];
      #pragma unroll
      for (int p=0;p<2;p++)
        #pragma unroll
        for (int q=0;q<2;q++)
          #pragma unroll
          for (int i=0;i<4;i++)
            #pragma unroll
            for (int j=0;j<4;j++)
              acc[p][q][i][j] += a[p][i] * b[q][j];
    }
  }

  #pragma unroll
  for (int p=0;p<2;p++)
    #pragma unroll
    for (int i=0;i<4;i++) {
      const int row = m0 + p*64 + ty*4 + i;
      #pragma unroll
      for (int q=0;q<2;q++) {
        const int col = n0 + q*64 + tx*4;
        float4 bb = *(const float4*)(b0 + col);
        float4 o;
        o.x = acc[p][q][i][0] + bb.x; o.y = acc[p][q][i][1] + bb.y;
        o.z = acc[p][q][i][2] + bb.z; o.w = acc[p][q][i][3] + bb.w;
        *(float4*)(X0G + (size_t)row*NG + col) = o;
      }
    }
}

// ---------------------------------------------------------------------------
// K_REC: persistent cooperative recurrence. 256 blocks x 512 threads.
// Block bx owns nh-columns {2bx, 2bx+1} of every gate and att-cols {2bx,2bx+1}.
// Weight slices (72 KB) live in LDS for all 20 steps.
// Wave w = (g<<1)|j handles gate g, col n0+j, rows lane & lane+64.
// 2 grid syncs per step; s0/s1 double-buffered. Race audit:
//   every cross-block read is >=1 grid.sync after its producing write, and
//   every buffer reuse is >=1 grid.sync after its last reader.
// ---------------------------------------------------------------------------
__global__ __launch_bounds__(512) void k_rec(
    const float* __restrict__ init,
    const float* __restrict__ W0,  const float* __restrict__ Watt,
    const float* __restrict__ batt, const float* __restrict__ W1,
    const float* __restrict__ b1,  const float* __restrict__ X0G,
    float* __restrict__ s0A, float* __restrict__ s0B,
    float* __restrict__ s1A, float* __restrict__ s1B,
    float* __restrict__ attb, float* __restrict__ H1,
    float* __restrict__ fin0, float* __restrict__ fin1)
{
  cg::grid_group grid = cg::this_grid();
  extern __shared__ float lds[];
  float* WT0  = lds;                 // [8][512]   16 KB  (W0 h-part, col-major)
  float* WTA  = WT0 + 8*512;         // [2][1024]   8 KB
  float* WT1  = WTA + 2*1024;        // [8][1536]  48 KB
  float* part = WT1 + 8*1536;        // [8][128]    4 KB  (gate/att partials)

  const int tid  = threadIdx.x;
  const int wv   = tid >> 6;         // wave 0..7
  const int lane = tid & 63;
  const int n0   = blockIdx.x * 2;   // owned nh / att-col base

  // ---- one-time: stage weight slices into LDS (uncoalesced but once) ----
  {
    const int col = ((wv >> 1) * 512) + n0 + (wv & 1);   // per-wave column
    for (int k = lane; k < 512; k += 64)
      WT0[wv*512 + k] = W0[(size_t)(1024 + k)*NG + col];
    for (int k = lane; k < 1536; k += 64)
      WT1[wv*1536 + k] = W1[(size_t)k*NG + col];
  }
  for (int idx = tid; idx < 2*1024; idx += 512) {
    const int c = idx >> 10, k = idx & 1023;
    WTA[idx] = Watt[(size_t)k*H + n0 + c];
  }
  __syncthreads();

  for (int t = 0; t < S; ++t) {
    const float* s0p = (t == 0) ? init            : ((t & 1) ? s0A : s0B);
    float*       s0c = (t & 1) ? s0B : s0A;
    const float* s1p = (t == 0) ? init + (size_t)B*HB : ((t & 1) ? s1A : s1B);
    float*       s1c = (t & 1) ? s1B : s1A;

    // ================= cell0: gates_h = h0_prev @ W0h ====================
    {
      float acc0 = 0.f, acc1 = 0.f;
      dotpair512(WT0 + wv*512, s0p + lane*HB, s0p + (lane+64)*HB, acc0, acc1);
      part[wv*128 + lane]      = acc0;
      part[wv*128 + lane + 64] = acc1;
    }
    __syncthreads();
    if (tid < 256) {                      // pointwise LSTM for (j, r)
      const int j = tid >> 7, r = tid & 127;
      const int nh = n0 + j;
      const float* xg = X0G + (size_t)(t*B + r)*NG;
      const float gi = part[(0*2+j)*128 + r] + xg[0*512 + nh];
      const float gf = part[(1*2+j)*128 + r] + xg[1*512 + nh];
      const float gg = part[(2*2+j)*128 + r] + xg[2*512 + nh];
      const float go = part[(3*2+j)*128 + r] + xg[3*512 + nh];
      const float c_old = s0p[r*HB + H + nh];
      const float c_new = sigf(gf)*c_old + sigf(gi)*tanhf(gg);
      const float h_new = sigf(go)*tanhf(c_new);
      s0c[r*HB + nh]     = h_new;
      s0c[r*HB + H + nh] = c_new;
      if (t == S-1) { fin0[r*HB + nh] = h_new; fin0[r*HB + H + nh] = c_new; }
    }
    grid.sync();   // SYNC1: s0c globally visible

    // ================= att: tanh([h0|c0] @ Watt + batt) ==================
    {
      const int ks = wv & 1, c = (wv >> 1) & 1, rh = wv >> 2;
      const int r = rh*64 + lane;
      const float p = dot512(WTA + c*1024 + ks*512, s0c + r*HB + ks*512);
      part[(ks*2 + c)*128 + r] = p;
    }
    __syncthreads();
    if (tid < 256) {
      const int c = tid >> 7, r = tid & 127;
      const float v = part[c*128 + r] + part[(2 + c)*128 + r] + batt[n0 + c];
      attb[r*H + n0 + c] = tanhf(v);
    }
    grid.sync();   // SYNC2: attb globally visible

    // ================= cell1: gates = [h0|att|h1p] @ W1 + b1 =============
    {
      float acc0 = 0.f, acc1 = 0.f;
      const float* wt = WT1 + wv*1536;
      dotpair512(wt,        s0c  + lane*HB, s0c  + (lane+64)*HB, acc0, acc1);
      dotpair512(wt + 512,  attb + lane*H,  attb + (lane+64)*H,  acc0, acc1);
      dotpair512(wt + 1024, s1p  + lane*HB, s1p  + (lane+64)*HB, acc0, acc1);
      part[wv*128 + lane]      = acc0;
      part[wv*128 + lane + 64] = acc1;
    }
    __syncthreads();
    if (tid < 256) {
      const int j = tid >> 7, r = tid & 127;
      const int nh = n0 + j;
      const float gi = part[(0*2+j)*128 + r] + b1[0*512 + nh];
      const float gf = part[(1*2+j)*128 + r] + b1[1*512 + nh];
      const float gg = part[(2*2+j)*128 + r] + b1[2*512 + nh];
      const float go = part[(3*2+j)*128 + r] + b1[3*512 + nh];
      const float c_old = s1p[r*HB + H + nh];
      const float c_new = sigf(gf)*c_old + sigf(gi)*tanhf(gg);
      const float h_new = sigf(go)*tanhf(c_new);
      s1c[r*HB + nh]     = h_new;
      s1c[r*HB + H + nh] = c_new;
      H1[(size_t)(t*B + r)*H + nh] = h_new;
      if (t == S-1) { fin1[r*HB + nh] = h_new; fin1[r*HB + H + nh] = c_new; }
    }
    __syncthreads();  // protect `part` from next iteration's cell0 writes
  }
}

// ---------------------------------------------------------------------------
// K5: logits[b][t][:] = H1[t*B+b] @ W_out + b_out.
// M=2560, N=10000, K=512. BM=BN=128, BK=8. grid(79,20), 256 thr.
// ---------------------------------------------------------------------------
__global__ __launch_bounds__(256) void k_logits(
    const float* __restrict__ H1, const float* __restrict__ Wout,
    const float* __restrict__ bout, float* __restrict__ out)
{
  __shared__ __align__(16) float As[8][128];
  __shared__ __align__(16) float Bs[8][128];
  const int tid = threadIdx.x;
  const int m0 = blockIdx.y * 128, n0 = blockIdx.x * 128;
  const int tx = tid & 15, ty = tid >> 4;

  const int rloc = tid >> 1;
  const int arow = m0 + rloc;
  const int ak4  = (tid & 1) * 4;
  const int bkk = tid >> 5;
  const int bc4 = (tid & 31) * 4;

  float acc[2][2][4][4];
  #pragma unroll
  for (int p=0;p<2;p++)
    #pragma unroll
    for (int q=0;q<2;q++)
      #pragma unroll
      for (int i=0;i<4;i++)
        #pragma unroll
        for (int j=0;j<4;j++) acc[p][q][i][j]=0.f;

  for (int kt = 0; kt < 512/8; ++kt) {
    float4 av = *(const float4*)(H1 + (size_t)arow*H + kt*8 + ak4);
    const int bcol = n0 + bc4;
    float4 bv = make_float4(0.f,0.f,0.f,0.f);
    if (bcol < V) bv = *(const float4*)(Wout + (size_t)(kt*8 + bkk)*V + bcol);
    __syncthreads();
    As[ak4+0][rloc] = av.x; As[ak4+1][rloc] = av.y;
    As[ak4+2][rloc] = av.z; As[ak4+3][rloc] = av.w;
    *(float4*)&Bs[bkk][bc4] = bv;
    __syncthreads();
    #pragma unroll
    for (int kk=0; kk<8; ++kk) {
      float a[2][4], b[2][4];
      *(float4*)a[0] = *(const float4*)&As[kk][ty*4];
      *(float4*)a[1] = *(const float4*)&As[kk][64 + ty*4];
      *(float4*)b[0] = *(const float4*)&Bs[kk][tx*4];
      *(float4*)b[1] = *(const float4*)&Bs[kk][64 + tx*4];
      #pragma unroll
      for (int p=0;p<2;p++)
        #pragma unroll
        for (int q=0;q<2;q++)
          #pragma unroll
          for (int i=0;i<4;i++)
            #pragma unroll
            for (int j=0;j<4;j++)
              acc[p][q][i][j] += a[p][i] * b[q][j];
    }
  }

  #pragma unroll
  for (int p=0;p<2;p++)
    #pragma unroll
    for (int i=0;i<4;i++) {
      const int row = m0 + p*64 + ty*4 + i;      // r = t*B + b
      const int t_ = row >> 7, b_ = row & 127;
      float* orow = out + ((size_t)b_*S + t_) * V;
      #pragma unroll
      for (int q=0;q<2;q++) {
        const int col = n0 + q*64 + tx*4;
        if (col < V) {
          float4 bb = *(const float4*)(bout + col);
          float4 o;
          o.x = acc[p][q][i][0] + bb.x; o.y = acc[p][q][i][1] + bb.y;
          o.z = acc[p][q][i][2] + bb.z; o.w = acc[p][q][i][3] + bb.w;
          *(float4*)(orow + col) = o;
        }
      }
    }
}

// ---------------------------------------------------------------------------
extern "C" void kernel_launch(void* const* d_in, const int* in_sizes, int n_in,
                              void* d_out, int out_size, void* d_ws, size_t ws_size,
                              hipStream_t stream) {
  const int*   tok  = (const int*)  d_in[0];
  const float* base = (const float*)d_in[1];
  const float* init = (const float*)d_in[2];
  const float* emb  = (const float*)d_in[3];
  const float* W0   = (const float*)d_in[4];
  const float* b0   = (const float*)d_in[5];
  const float* W1   = (const float*)d_in[6];
  const float* b1   = (const float*)d_in[7];
  const float* Watt = (const float*)d_in[8];
  const float* batt = (const float*)d_in[9];
  const float* Wout = (const float*)d_in[10];
  const float* bout = (const float*)d_in[11];
  float* out = (float*)d_out;

  float* ws   = (float*)d_ws;
  float* X0G  = ws;                          // 2560*2048
  float* s0A  = X0G + (size_t)2560*NG;       // B*HB each
  float* s0B  = s0A + (size_t)B*HB;
  float* s1A  = s0B + (size_t)B*HB;
  float* s1B  = s1A + (size_t)B*HB;
  float* attb = s1B + (size_t)B*HB;          // B*H
  float* H1   = attb + (size_t)B*H;          // 2560*512

  float* fin0 = out + (size_t)B*S*V;         // final_state layer 0
  float* fin1 = fin0 + (size_t)B*HB;         // final_state layer 1

  k_x0g<<<dim3(16,20),256,0,stream>>>(tok, base, emb, W0, b0, X0G);

  const unsigned int REC_LDS = (8*512 + 2*1024 + 8*1536 + 8*128) * 4; // 77824 B
  hipFuncSetAttribute((const void*)k_rec,
                      hipFuncAttributeMaxDynamicSharedMemorySize, REC_LDS);
  void* args[] = { (void*)&init, (void*)&W0, (void*)&Watt, (void*)&batt,
                   (void*)&W1, (void*)&b1, (void*)&X0G,
                   (void*)&s0A, (void*)&s0B, (void*)&s1A, (void*)&s1B,
                   (void*)&attb, (void*)&H1, (void*)&fin0, (void*)&fin1 };
  hipLaunchCooperativeKernel((void*)k_rec, dim3(256), dim3(512),
                             args, REC_LDS, stream);

  k_logits<<<dim3(79,20),256,0,stream>>>(H1, Wout, bout, out);
}

// Round 6
// 2888.696 us; speedup vs baseline: 2.4772x; 2.4772x over previous
//
#include <hip/hip_runtime.h>
#include <hip/hip_cooperative_groups.h>
#include <math.h>

namespace cg = cooperative_groups;

#define B 128
#define S 20
#define H 512
#define E 512
#define V 10000
#define NG 2048   // 4*H (gate width)
#define HB 1024   // 2*H (state row width)

__device__ __forceinline__ float sigf(float x) { return 1.0f / (1.0f + expf(-x)); }

// ---------------------------------------------------------------------------
// K0: transpose initial_state [2][128][1024] -> initT [2][1024][128]
// coalesced writes (out index thread-fast); scattered reads (one-time, ~1MB)
// ---------------------------------------------------------------------------
__global__ __launch_bounds__(256) void k_tr_init(
    const float* __restrict__ init, float* __restrict__ initT)
{
  const int idx0 = blockIdx.x * 256 + threadIdx.x;   // grid 256 -> 65536 thr
  #pragma unroll
  for (int i = 0; i < 4; ++i) {
    const int o = idx0 + i * 65536;                  // 0..262143
    const int r = o & 127;
    const int k = (o >> 7) & 1023;
    const int l = o >> 17;
    initT[o] = init[(size_t)(l * 128 + r) * 1024 + k];
  }
}

// ---------------------------------------------------------------------------
// K1: X0G[t*B+b][n] = concat(baseimg[b], emb[tok[b][t]]) @ W0[0:1024,:] + b0
// M=2560, N=2048, K=1024.  Row-major output (pointwise reads it sparsely).
// ---------------------------------------------------------------------------
__global__ __launch_bounds__(256) void k_x0g(
    const int* __restrict__ tok, const float* __restrict__ base,
    const float* __restrict__ emb, const float* __restrict__ W0,
    const float* __restrict__ b0, float* __restrict__ X0G)
{
  __shared__ __align__(16) float As[8][128];
  __shared__ __align__(16) float Bs[8][128];
  const int tid = threadIdx.x;
  const int m0 = blockIdx.y * 128, n0 = blockIdx.x * 128;
  const int tx = tid & 15, ty = tid >> 4;

  const int rloc = tid >> 1;
  const int arow = m0 + rloc;
  const int ak4  = (tid & 1) * 4;
  const int t_ = arow >> 7, b_ = arow & 127;
  const int token = tok[b_ * S + t_];
  const float* arow_lo = base + (size_t)b_ * E;
  const float* arow_hi = emb + (size_t)token * E;

  const int bkk = tid >> 5;
  const int bc4 = (tid & 31) * 4;

  float acc[2][2][4][4];
  #pragma unroll
  for (int p=0;p<2;p++)
    #pragma unroll
    for (int q=0;q<2;q++)
      #pragma unroll
      for (int i=0;i<4;i++)
        #pragma unroll
        for (int j=0;j<4;j++) acc[p][q][i][j]=0.f;

  for (int kt = 0; kt < 1024/8; ++kt) {
    const int k = kt*8 + ak4;
    float4 av = (k < 512) ? *(const float4*)(arow_lo + k)
                          : *(const float4*)(arow_hi + (k - 512));
    float4 bv = *(const float4*)(W0 + (size_t)(kt*8 + bkk)*NG + n0 + bc4);
    __syncthreads();
    As[ak4+0][rloc] = av.x; As[ak4+1][rloc] = av.y;
    As[ak4+2][rloc] = av.z; As[ak4+3][rloc] = av.w;
    *(float4*)&Bs[bkk][bc4] = bv;
    __syncthreads();
    #pragma unroll
    for (int kk=0; kk<8; ++kk) {
      float a[2][4], b[2][4];
      *(float4*)a[0] = *(const float4*)&As[kk][ty*4];
      *(float4*)a[1] = *(const float4*)&As[kk][64 + ty*4];
      *(float4*)b[0] = *(const float4*)&Bs[kk][tx*4];
      *(float4*)b[1] = *(const float4*)&Bs[kk][64 + tx*4];
      #pragma unroll
      for (int p=0;p<2;p++)
        #pragma unroll
        for (int q=0;q<2;q++)
          #pragma unroll
          for (int i=0;i<4;i++)
            #pragma unroll
            for (int j=0;j<4;j++)
              acc[p][q][i][j] += a[p][i] * b[q][j];
    }
  }

  #pragma unroll
  for (int p=0;p<2;p++)
    #pragma unroll
    for (int i=0;i<4;i++) {
      const int row = m0 + p*64 + ty*4 + i;
      #pragma unroll
      for (int q=0;q<2;q++) {
        const int col = n0 + q*64 + tx*4;
        float4 bb = *(const float4*)(b0 + col);
        float4 o;
        o.x = acc[p][q][i][0] + bb.x; o.y = acc[p][q][i][1] + bb.y;
        o.z = acc[p][q][i][2] + bb.z; o.w = acc[p][q][i][3] + bb.w;
        *(float4*)(X0G + (size_t)row*NG + col) = o;
      }
    }
}

// ---------------------------------------------------------------------------
// K_REC v3: persistent cooperative recurrence, TRANSPOSED state.
//   State buffers sT[k][r]: s0T/s1T are [1024][128] (h rows 0..511, c 512..1023),
//   attT [512][128], H1T [S][512][128]. All lane-indexed reads/writes r-fast.
// 256 blocks x 512 threads (8 waves). Block bx owns nh cols {2bx, 2bx+1}
//   => 8 gate-cols c=(g<<1)|j. Waves split K (wave ks covers K/8), each wave
//   computes ALL 8 cols: acc[8][2] (rows lane, lane+64). 16 FMA per 2 loads.
//   Partials -> LDS part[ks][c][r] -> tree reduce -> pointwise (tid<256).
// Weight slices in LDS as [k][c] (76 KB), staged once.
// 2 grid syncs/step; s0/s1 double-buffered (race schedule as before).
// ---------------------------------------------------------------------------
__global__ __launch_bounds__(512) void k_rec(
    const float* __restrict__ initT,
    const float* __restrict__ W0,  const float* __restrict__ Watt,
    const float* __restrict__ batt, const float* __restrict__ W1,
    const float* __restrict__ b1,  const float* __restrict__ X0G,
    float* __restrict__ s0AT, float* __restrict__ s0BT,
    float* __restrict__ s1AT, float* __restrict__ s1BT,
    float* __restrict__ attT, float* __restrict__ H1T,
    float* __restrict__ fin0, float* __restrict__ fin1)
{
  cg::grid_group grid = cg::this_grid();
  extern __shared__ float lds[];
  float* WT0  = lds;                 // [512][8]   16 KB  w0h[k][c]
  float* WTA  = WT0 + 512*8;         // [1024][2]   8 KB
  float* WT1  = WTA + 1024*2;        // [1536][8]  48 KB
  float* part = WT1 + 1536*8;        // [8][8][128] 32 KB  partials [ks][c][r]
  float* gred = part + 8*8*128;      // [8][128]    4 KB   reduced gates [c][r]

  const int tid  = threadIdx.x;
  const int wv   = tid >> 6;         // wave = K-slice index 0..7
  const int lane = tid & 63;
  const int n0   = blockIdx.x * 2;   // owned nh pair

  // ---- one-time weight staging:  WT[k][c], c=(g<<1)|j -> col g*512+n0+j ----
  for (int idx = tid; idx < 512*8; idx += 512) {
    const int k = idx >> 3, c = idx & 7;
    WT0[idx] = W0[(size_t)(1024 + k)*NG + (c>>1)*512 + n0 + (c&1)];
  }
  for (int idx = tid; idx < 1536*8; idx += 512) {
    const int k = idx >> 3, c = idx & 7;
    WT1[idx] = W1[(size_t)k*NG + (c>>1)*512 + n0 + (c&1)];
  }
  for (int idx = tid; idx < 1024*2; idx += 512) {
    const int k = idx >> 1, c = idx & 1;
    WTA[idx] = Watt[(size_t)k*H + n0 + c];
  }
  __syncthreads();

  for (int t = 0; t < S; ++t) {
    const float* s0pT = (t == 0) ? initT : ((t & 1) ? s0AT : s0BT);
    float*       s0cT = (t & 1) ? s0BT : s0AT;
    const float* s1pT = (t == 0) ? initT + 1024*128 : ((t & 1) ? s1AT : s1BT);
    float*       s1cT = (t & 1) ? s1BT : s1AT;

    // ================= cell0: gates_h = h0_prev @ W0h  (K=512) ===========
    {
      float acc[8][2];
      #pragma unroll
      for (int c=0;c<8;c++){acc[c][0]=0.f;acc[c][1]=0.f;}
      const float* ap = s0pT + (size_t)(wv*64)*128 + lane;   // h rows only
      const float* wp = WT0 + (wv*64)*8;
      #pragma unroll 8
      for (int kk = 0; kk < 64; ++kk) {
        const float a0 = ap[kk*128];
        const float a1 = ap[kk*128 + 64];
        const float4 wA = *(const float4*)(wp + kk*8);
        const float4 wB = *(const float4*)(wp + kk*8 + 4);
        acc[0][0]=fmaf(wA.x,a0,acc[0][0]); acc[0][1]=fmaf(wA.x,a1,acc[0][1]);
        acc[1][0]=fmaf(wA.y,a0,acc[1][0]); acc[1][1]=fmaf(wA.y,a1,acc[1][1]);
        acc[2][0]=fmaf(wA.z,a0,acc[2][0]); acc[2][1]=fmaf(wA.z,a1,acc[2][1]);
        acc[3][0]=fmaf(wA.w,a0,acc[3][0]); acc[3][1]=fmaf(wA.w,a1,acc[3][1]);
        acc[4][0]=fmaf(wB.x,a0,acc[4][0]); acc[4][1]=fmaf(wB.x,a1,acc[4][1]);
        acc[5][0]=fmaf(wB.y,a0,acc[5][0]); acc[5][1]=fmaf(wB.y,a1,acc[5][1]);
        acc[6][0]=fmaf(wB.z,a0,acc[6][0]); acc[6][1]=fmaf(wB.z,a1,acc[6][1]);
        acc[7][0]=fmaf(wB.w,a0,acc[7][0]); acc[7][1]=fmaf(wB.w,a1,acc[7][1]);
      }
      #pragma unroll
      for (int c=0;c<8;c++) {
        part[(wv*8 + c)*128 + lane]      = acc[c][0];
        part[(wv*8 + c)*128 + lane + 64] = acc[c][1];
      }
    }
    __syncthreads();
    // reduce 8 K-slices -> gred[c][r]
    for (int o = tid; o < 1024; o += 512) {
      const int c = o >> 7, r = o & 127;
      float s = 0.f;
      #pragma unroll
      for (int ks=0; ks<8; ++ks) s += part[(ks*8 + c)*128 + r];
      gred[c*128 + r] = s;
    }
    __syncthreads();
    if (tid < 256) {                       // pointwise LSTM (r, j)
      const int r = tid & 127, j = tid >> 7;
      const int nh = n0 + j;
      const float* xg = X0G + (size_t)(t*B + r)*NG;
      const float gi = gred[(0*2+j)*128 + r] + xg[0*512 + nh];
      const float gf = gred[(1*2+j)*128 + r] + xg[1*512 + nh];
      const float gg = gred[(2*2+j)*128 + r] + xg[2*512 + nh];
      const float go = gred[(3*2+j)*128 + r] + xg[3*512 + nh];
      const float c_old = s0pT[(512 + nh)*128 + r];          // coalesced
      const float c_new = sigf(gf)*c_old + sigf(gi)*tanhf(gg);
      const float h_new = sigf(go)*tanhf(c_new);
      s0cT[nh*128 + r]         = h_new;                      // coalesced
      s0cT[(512 + nh)*128 + r] = c_new;
      if (t == S-1) { fin0[r*HB + nh] = h_new; fin0[r*HB + H + nh] = c_new; }
    }
    grid.sync();   // SYNC1: s0cT globally visible

    // ================= att: tanh([h|c] @ Watt + batt)  (K=1024, C=2) =====
    {
      float acc[2][2];
      acc[0][0]=0.f;acc[0][1]=0.f;acc[1][0]=0.f;acc[1][1]=0.f;
      const float* ap = s0cT + (size_t)(wv*128)*128 + lane;  // full [h|c]
      const float* wp = WTA + (wv*128)*2;
      #pragma unroll 8
      for (int kk = 0; kk < 128; ++kk) {
        const float a0 = ap[kk*128];
        const float a1 = ap[kk*128 + 64];
        const float2 w = *(const float2*)(wp + kk*2);
        acc[0][0]=fmaf(w.x,a0,acc[0][0]); acc[0][1]=fmaf(w.x,a1,acc[0][1]);
        acc[1][0]=fmaf(w.y,a0,acc[1][0]); acc[1][1]=fmaf(w.y,a1,acc[1][1]);
      }
      part[(wv*8 + 0)*128 + lane]      = acc[0][0];
      part[(wv*8 + 0)*128 + lane + 64] = acc[0][1];
      part[(wv*8 + 1)*128 + lane]      = acc[1][0];
      part[(wv*8 + 1)*128 + lane + 64] = acc[1][1];
    }
    __syncthreads();
    if (tid < 256) {
      const int r = tid & 127, c = tid >> 7;
      float s = 0.f;
      #pragma unroll
      for (int ks=0; ks<8; ++ks) s += part[(ks*8 + c)*128 + r];
      attT[(n0 + c)*128 + r] = tanhf(s + batt[n0 + c]);      // coalesced
    }
    grid.sync();   // SYNC2: attT globally visible

    // ================= cell1: gates = [h0|att|h1p] @ W1  (K=3x512) =======
    {
      float acc[8][2];
      #pragma unroll
      for (int c=0;c<8;c++){acc[c][0]=0.f;acc[c][1]=0.f;}
      #pragma unroll
      for (int seg = 0; seg < 3; ++seg) {
        const float* srcT = (seg == 0) ? s0cT : (seg == 1) ? attT : s1pT;
        const float* ap = srcT + (size_t)(wv*64)*128 + lane;  // h rows 0..511
        const float* wp = WT1 + (seg*512 + wv*64)*8;
        #pragma unroll 8
        for (int kk = 0; kk < 64; ++kk) {
          const float a0 = ap[kk*128];
          const float a1 = ap[kk*128 + 64];
          const float4 wA = *(const float4*)(wp + kk*8);
          const float4 wB = *(const float4*)(wp + kk*8 + 4);
          acc[0][0]=fmaf(wA.x,a0,acc[0][0]); acc[0][1]=fmaf(wA.x,a1,acc[0][1]);
          acc[1][0]=fmaf(wA.y,a0,acc[1][0]); acc[1][1]=fmaf(wA.y,a1,acc[1][1]);
          acc[2][0]=fmaf(wA.z,a0,acc[2][0]); acc[2][1]=fmaf(wA.z,a1,acc[2][1]);
          acc[3][0]=fmaf(wA.w,a0,acc[3][0]); acc[3][1]=fmaf(wA.w,a1,acc[3][1]);
          acc[4][0]=fmaf(wB.x,a0,acc[4][0]); acc[4][1]=fmaf(wB.x,a1,acc[4][1]);
          acc[5][0]=fmaf(wB.y,a0,acc[5][0]); acc[5][1]=fmaf(wB.y,a1,acc[5][1]);
          acc[6][0]=fmaf(wB.z,a0,acc[6][0]); acc[6][1]=fmaf(wB.z,a1,acc[6][1]);
          acc[7][0]=fmaf(wB.w,a0,acc[7][0]); acc[7][1]=fmaf(wB.w,a1,acc[7][1]);
        }
      }
      #pragma unroll
      for (int c=0;c<8;c++) {
        part[(wv*8 + c)*128 + lane]      = acc[c][0];
        part[(wv*8 + c)*128 + lane + 64] = acc[c][1];
      }
    }
    __syncthreads();
    for (int o = tid; o < 1024; o += 512) {
      const int c = o >> 7, r = o & 127;
      float s = 0.f;
      #pragma unroll
      for (int ks=0; ks<8; ++ks) s += part[(ks*8 + c)*128 + r];
      gred[c*128 + r] = s;
    }
    __syncthreads();
    if (tid < 256) {
      const int r = tid & 127, j = tid >> 7;
      const int nh = n0 + j;
      const float gi = gred[(0*2+j)*128 + r] + b1[0*512 + nh];
      const float gf = gred[(1*2+j)*128 + r] + b1[1*512 + nh];
      const float gg = gred[(2*2+j)*128 + r] + b1[2*512 + nh];
      const float go = gred[(3*2+j)*128 + r] + b1[3*512 + nh];
      const float c_old = s1pT[(512 + nh)*128 + r];
      const float c_new = sigf(gf)*c_old + sigf(gi)*tanhf(gg);
      const float h_new = sigf(go)*tanhf(c_new);
      s1cT[nh*128 + r]         = h_new;
      s1cT[(512 + nh)*128 + r] = c_new;
      H1T[((size_t)t*512 + nh)*128 + r] = h_new;             // coalesced
      if (t == S-1) { fin1[r*HB + nh] = h_new; fin1[r*HB + H + nh] = c_new; }
    }
    __syncthreads();  // protect part/gred before next step's cell0 writes
  }
}

// ---------------------------------------------------------------------------
// K5: logits[b][t][:] = H1T-row @ W_out + b_out.
// M=2560 (=20 t-tiles of 128), N=10000, K=512.  A read from H1T[t][k][b]
// (fully coalesced; As layout [k][row] unchanged from before).
// ---------------------------------------------------------------------------
__global__ __launch_bounds__(256) void k_logits(
    const float* __restrict__ H1T, const float* __restrict__ Wout,
    const float* __restrict__ bout, float* __restrict__ out)
{
  __shared__ __align__(16) float As[8][128];
  __shared__ __align__(16) float Bs[8][128];
  const int tid = threadIdx.x;
  const int m0 = blockIdx.y * 128, n0 = blockIdx.x * 128;
  const int tt = blockIdx.y;                 // t index (m-tile == one t)
  const int tx = tid & 15, ty = tid >> 4;

  const int akk = tid >> 5;                  // 0..7   (k within tile)
  const int ab4 = (tid & 31) * 4;            // 0..124 (b, float4)
  const int bkk = tid >> 5;
  const int bc4 = (tid & 31) * 4;

  float acc[2][2][4][4];
  #pragma unroll
  for (int p=0;p<2;p++)
    #pragma unroll
    for (int q=0;q<2;q++)
      #pragma unroll
      for (int i=0;i<4;i++)
        #pragma unroll
        for (int j=0;j<4;j++) acc[p][q][i][j]=0.f;

  for (int kt = 0; kt < 512/8; ++kt) {
    float4 av = *(const float4*)(H1T + ((size_t)tt*512 + kt*8 + akk)*128 + ab4);
    const int bcol = n0 + bc4;
    float4 bv = make_float4(0.f,0.f,0.f,0.f);
    if (bcol < V) bv = *(const float4*)(Wout + (size_t)(kt*8 + bkk)*V + bcol);
    __syncthreads();
    *(float4*)&As[akk][ab4] = av;
    *(float4*)&Bs[bkk][bc4] = bv;
    __syncthreads();
    #pragma unroll
    for (int kk=0; kk<8; ++kk) {
      float a[2][4], b[2][4];
      *(float4*)a[0] = *(const float4*)&As[kk][ty*4];
      *(float4*)a[1] = *(const float4*)&As[kk][64 + ty*4];
      *(float4*)b[0] = *(const float4*)&Bs[kk][tx*4];
      *(float4*)b[1] = *(const float4*)&Bs[kk][64 + tx*4];
      #pragma unroll
      for (int p=0;p<2;p++)
        #pragma unroll
        for (int q=0;q<2;q++)
          #pragma unroll
          for (int i=0;i<4;i++)
            #pragma unroll
            for (int j=0;j<4;j++)
              acc[p][q][i][j] += a[p][i] * b[q][j];
    }
  }

  #pragma unroll
  for (int p=0;p<2;p++)
    #pragma unroll
    for (int i=0;i<4;i++) {
      const int row = m0 + p*64 + ty*4 + i;      // r = t*B + b
      const int t_ = row >> 7, b_ = row & 127;
      float* orow = out + ((size_t)b_*S + t_) * V;
      #pragma unroll
      for (int q=0;q<2;q++) {
        const int col = n0 + q*64 + tx*4;
        if (col < V) {
          float4 bb = *(const float4*)(bout + col);
          float4 o;
          o.x = acc[p][q][i][0] + bb.x; o.y = acc[p][q][i][1] + bb.y;
          o.z = acc[p][q][i][2] + bb.z; o.w = acc[p][q][i][3] + bb.w;
          *(float4*)(orow + col) = o;
        }
      }
    }
}

// ---------------------------------------------------------------------------
extern "C" void kernel_launch(void* const* d_in, const int* in_sizes, int n_in,
                              void* d_out, int out_size, void* d_ws, size_t ws_size,
                              hipStream_t stream) {
  const int*   tok  = (const int*)  d_in[0];
  const float* base = (const float*)d_in[1];
  const float* init = (const float*)d_in[2];
  const float* emb  = (const float*)d_in[3];
  const float* W0   = (const float*)d_in[4];
  const float* b0   = (const float*)d_in[5];
  const float* W1   = (const float*)d_in[6];
  const float* b1   = (const float*)d_in[7];
  const float* Watt = (const float*)d_in[8];
  const float* batt = (const float*)d_in[9];
  const float* Wout = (const float*)d_in[10];
  const float* bout = (const float*)d_in[11];
  float* out = (float*)d_out;

  float* ws    = (float*)d_ws;
  float* X0G   = ws;                          // 2560*2048   = 5,242,880
  float* s0AT  = X0G  + (size_t)2560*NG;      // 1024*128 each
  float* s0BT  = s0AT + 1024*128;
  float* s1AT  = s0BT + 1024*128;
  float* s1BT  = s1AT + 1024*128;
  float* attT  = s1BT + 1024*128;             // 512*128
  float* H1T   = attT + 512*128;              // 20*512*128 = 1,310,720
  float* initT = H1T  + (size_t)S*512*128;    // 2*1024*128 = 262,144

  float* fin0 = out + (size_t)B*S*V;          // final_state layer 0
  float* fin1 = fin0 + (size_t)B*HB;          // final_state layer 1

  k_tr_init<<<256, 256, 0, stream>>>(init, initT);
  k_x0g<<<dim3(16,20),256,0,stream>>>(tok, base, emb, W0, b0, X0G);

  const unsigned int REC_LDS = (512*8 + 1024*2 + 1536*8 + 8*8*128 + 8*128) * 4; // 110,592 B
  hipFuncSetAttribute((const void*)k_rec,
                      hipFuncAttributeMaxDynamicSharedMemorySize, REC_LDS);
  void* args[] = { (void*)&initT, (void*)&W0, (void*)&Watt, (void*)&batt,
                   (void*)&W1, (void*)&b1, (void*)&X0G,
                   (void*)&s0AT, (void*)&s0BT, (void*)&s1AT, (void*)&s1BT,
                   (void*)&attT, (void*)&H1T, (void*)&fin0, (void*)&fin1 };
  hipLaunchCooperativeKernel((void*)k_rec, dim3(256), dim3(512),
                             args, REC_LDS, stream);

  k_logits<<<dim3(79,20),256,0,stream>>>(H1T, Wout, bout, out);
}

// Round 8
// 1891.604 us; speedup vs baseline: 3.7829x; 1.5271x over previous
//
#include <hip/hip_runtime.h>
#include <hip/hip_cooperative_groups.h>
#include <math.h>

namespace cg = cooperative_groups;

#define B 128
#define S 20
#define H 512
#define E 512
#define V 10000
#define NG 2048   // 4*H
#define HB 1024   // 2*H

__device__ __forceinline__ float sigf(float x) { return 1.0f / (1.0f + expf(-x)); }

// ---- 8-col FMA block: 8 k-values, cols via LDS weights [k][8] ----
__device__ __forceinline__ void fma_blk8(const float2* a0, const float* wkc,
                                         float2* acc) {
  #pragma unroll
  for (int i = 0; i < 8; ++i) {
    const float4 wA = *(const float4*)(wkc + i*8);
    const float4 wB = *(const float4*)(wkc + i*8 + 4);
    const float2 a = a0[i];
    acc[0].x=fmaf(wA.x,a.x,acc[0].x); acc[0].y=fmaf(wA.x,a.y,acc[0].y);
    acc[1].x=fmaf(wA.y,a.x,acc[1].x); acc[1].y=fmaf(wA.y,a.y,acc[1].y);
    acc[2].x=fmaf(wA.z,a.x,acc[2].x); acc[2].y=fmaf(wA.z,a.y,acc[2].y);
    acc[3].x=fmaf(wA.w,a.x,acc[3].x); acc[3].y=fmaf(wA.w,a.y,acc[3].y);
    acc[4].x=fmaf(wB.x,a.x,acc[4].x); acc[4].y=fmaf(wB.x,a.y,acc[4].y);
    acc[5].x=fmaf(wB.y,a.x,acc[5].x); acc[5].y=fmaf(wB.y,a.y,acc[5].y);
    acc[6].x=fmaf(wB.z,a.x,acc[6].x); acc[6].y=fmaf(wB.z,a.y,acc[6].y);
    acc[7].x=fmaf(wB.w,a.x,acc[7].x); acc[7].y=fmaf(wB.w,a.y,acc[7].y);
  }
}
__device__ __forceinline__ void fma_blk2(const float2* a0, const float* wkc,
                                         float2* acc) {
  #pragma unroll
  for (int i = 0; i < 8; ++i) {
    const float2 w = *(const float2*)(wkc + i*2);
    const float2 a = a0[i];
    acc[0].x=fmaf(w.x,a.x,acc[0].x); acc[0].y=fmaf(w.x,a.y,acc[0].y);
    acc[1].x=fmaf(w.y,a.x,acc[1].x); acc[1].y=fmaf(w.y,a.y,acc[1].y);
  }
}

// K-slice dot, 8 cols: state sT=[k][128] (r fast), rows (2*lane, 2*lane+1).
// Double-buffered 8-deep register staging to keep ~16 loads in flight.
__device__ __forceinline__ void dot_k8(const float* __restrict__ sT,
                                       const float* __restrict__ wk,
                                       const int lane, const int nk,
                                       float2* __restrict__ acc) {
  const float2* ap = (const float2*)sT + lane;   // stride 64 float2 per k
  float2 a0[8], a1[8];
  #pragma unroll
  for (int i = 0; i < 8; ++i) a0[i] = ap[i*64];
  int kc = 0;
  for (; kc + 8 < nk; kc += 8) {
    #pragma unroll
    for (int i = 0; i < 8; ++i) a1[i] = ap[(kc + 8 + i)*64];
    fma_blk8(a0, wk + kc*8, acc);
    #pragma unroll
    for (int i = 0; i < 8; ++i) a0[i] = a1[i];
  }
  fma_blk8(a0, wk + kc*8, acc);
}
__device__ __forceinline__ void dot_k2(const float* __restrict__ sT,
                                       const float* __restrict__ wk,
                                       const int lane, const int nk,
                                       float2* __restrict__ acc) {
  const float2* ap = (const float2*)sT + lane;
  float2 a0[8], a1[8];
  #pragma unroll
  for (int i = 0; i < 8; ++i) a0[i] = ap[i*64];
  int kc = 0;
  for (; kc + 8 < nk; kc += 8) {
    #pragma unroll
    for (int i = 0; i < 8; ++i) a1[i] = ap[(kc + 8 + i)*64];
    fma_blk2(a0, wk + kc*2, acc);
    #pragma unroll
    for (int i = 0; i < 8; ++i) a0[i] = a1[i];
  }
  fma_blk2(a0, wk + kc*2, acc);
}

// ---------------------------------------------------------------------------
// K0: transpose initial_state [2][128][1024] -> initT [2][1024][128]
// ---------------------------------------------------------------------------
__global__ __launch_bounds__(256) void k_tr_init(
    const float* __restrict__ init, float* __restrict__ initT)
{
  const int idx0 = blockIdx.x * 256 + threadIdx.x;
  #pragma unroll
  for (int i = 0; i < 4; ++i) {
    const int o = idx0 + i * 65536;
    const int r = o & 127;
    const int k = (o >> 7) & 1023;
    const int l = o >> 17;
    initT[o] = init[(size_t)(l * 128 + r) * 1024 + k];
  }
}

// ---------------------------------------------------------------------------
// K1: X0GT[t][n][b] = (concat(baseimg[b], emb[tok[b][t]]) @ W0[0:1024,:] + b0)
// M=2560, N=2048, K=1024; output written TRANSPOSED (n-major, b fast) with
// full-cacheline float4 stores (i-index is the b dimension).
// ---------------------------------------------------------------------------
__global__ __launch_bounds__(256) void k_x0g(
    const int* __restrict__ tok, const float* __restrict__ base,
    const float* __restrict__ emb, const float* __restrict__ W0,
    const float* __restrict__ b0, float* __restrict__ X0GT)
{
  __shared__ __align__(16) float As[8][128];
  __shared__ __align__(16) float Bs[8][128];
  const int tid = threadIdx.x;
  const int m0 = blockIdx.y * 128, n0 = blockIdx.x * 128;
  const int tt = blockIdx.y;                 // one m-tile == one t
  const int tx = tid & 15, ty = tid >> 4;

  const int rloc = tid >> 1;
  const int arow = m0 + rloc;
  const int ak4  = (tid & 1) * 4;
  const int t_ = arow >> 7, b_ = arow & 127;
  const int token = tok[b_ * S + t_];
  const float* arow_lo = base + (size_t)b_ * E;
  const float* arow_hi = emb + (size_t)token * E;

  const int bkk = tid >> 5;
  const int bc4 = (tid & 31) * 4;

  float acc[2][2][4][4];
  #pragma unroll
  for (int p=0;p<2;p++)
    #pragma unroll
    for (int q=0;q<2;q++)
      #pragma unroll
      for (int i=0;i<4;i++)
        #pragma unroll
        for (int j=0;j<4;j++) acc[p][q][i][j]=0.f;

  for (int kt = 0; kt < 1024/8; ++kt) {
    const int k = kt*8 + ak4;
    float4 av = (k < 512) ? *(const float4*)(arow_lo + k)
                          : *(const float4*)(arow_hi + (k - 512));
    float4 bv = *(const float4*)(W0 + (size_t)(kt*8 + bkk)*NG + n0 + bc4);
    __syncthreads();
    As[ak4+0][rloc] = av.x; As[ak4+1][rloc] = av.y;
    As[ak4+2][rloc] = av.z; As[ak4+3][rloc] = av.w;
    *(float4*)&Bs[bkk][bc4] = bv;
    __syncthreads();
    #pragma unroll
    for (int kk=0; kk<8; ++kk) {
      float a[2][4], b[2][4];
      *(float4*)a[0] = *(const float4*)&As[kk][ty*4];
      *(float4*)a[1] = *(const float4*)&As[kk][64 + ty*4];
      *(float4*)b[0] = *(const float4*)&Bs[kk][tx*4];
      *(float4*)b[1] = *(const float4*)&Bs[kk][64 + tx*4];
      #pragma unroll
      for (int p=0;p<2;p++)
        #pragma unroll
        for (int q=0;q<2;q++)
          #pragma unroll
          for (int i=0;i<4;i++)
            #pragma unroll
            for (int j=0;j<4;j++)
              acc[p][q][i][j] += a[p][i] * b[q][j];
    }
  }

  // transposed epilogue: b-dim (i) is contiguous -> float4 stores
  #pragma unroll
  for (int p=0;p<2;p++)
    #pragma unroll
    for (int q=0;q<2;q++)
      #pragma unroll
      for (int j=0;j<4;j++) {
        const int col = n0 + q*64 + tx*4 + j;
        const float bb = b0[col];
        float4 v;
        v.x = acc[p][q][0][j] + bb; v.y = acc[p][q][1][j] + bb;
        v.z = acc[p][q][2][j] + bb; v.w = acc[p][q][3][j] + bb;
        *(float4*)(X0GT + ((size_t)tt*NG + col)*128 + p*64 + ty*4) = v;
      }
}

// ---------------------------------------------------------------------------
// K_REC v4: persistent cooperative recurrence, 1 grid.sync per step.
// Pipeline: phase(t) = { cell1(t) || att(t+1) || cell0(t+2) }.
//   s0 triple-buffered (read t, read t+1, write t+2); s1, att double-buffered.
// 256 blocks x 512 thr; block owns nh pair {2bx,2bx+1}; waves K-split (8).
// State layout [k][r] r-fast; rows per lane = (2*lane, 2*lane+1) via float2.
// Weights in LDS [k][c] staged once (72 KB); partials 42 KB. LDS = 144 KB.
// ---------------------------------------------------------------------------
__global__ __launch_bounds__(512, 2) void k_rec(
    const float* __restrict__ initT,
    const float* __restrict__ W0,  const float* __restrict__ Watt,
    const float* __restrict__ batt, const float* __restrict__ W1,
    const float* __restrict__ b1,  const float* __restrict__ X0GT,
    float* __restrict__ s0b0, float* __restrict__ s0b1, float* __restrict__ s0b2,
    float* __restrict__ s1b0, float* __restrict__ s1b1,
    float* __restrict__ at0,  float* __restrict__ at1,
    float* __restrict__ H1T,
    float* __restrict__ fin0, float* __restrict__ fin1)
{
  cg::grid_group grid = cg::this_grid();
  extern __shared__ float lds[];
  float* WT0     = lds;              // [512][8]    16 KB
  float* WTA     = WT0 + 4096;       // [1024][2]    8 KB
  float* WT1     = WTA + 2048;       // [1536][8]   48 KB
  float* part1   = WT1 + 12288;      // [8][8][128] 32 KB  cell1 partials
  float* part0   = part1 + 8192;     // [8][8][128] 32 KB  cell0 partials
  float* attpart = part0 + 8192;     // [8][2][128]  8 KB  att partials

  const int tid  = threadIdx.x;
  const int wv   = tid >> 6;
  const int lane = tid & 63;
  const int n0   = blockIdx.x * 2;

  float* s0b[3] = {s0b0, s0b1, s0b2};
  float* s1b[2] = {s1b0, s1b1};
  float* atb[2] = {at0, at1};

  // ---- one-time weight staging: WT[k][c], c=(g<<1)|j -> col g*512+n0+j ----
  for (int idx = tid; idx < 512*8; idx += 512) {
    const int k = idx >> 3, c = idx & 7;
    WT0[idx] = W0[(size_t)(1024 + k)*NG + (c>>1)*512 + n0 + (c&1)];
  }
  for (int idx = tid; idx < 1536*8; idx += 512) {
    const int k = idx >> 3, c = idx & 7;
    WT1[idx] = W1[(size_t)k*NG + (c>>1)*512 + n0 + (c&1)];
  }
  for (int idx = tid; idx < 1024*2; idx += 512) {
    const int k = idx >> 1, c = idx & 1;
    WTA[idx] = Watt[(size_t)k*H + n0 + c];
  }
  __syncthreads();

  // ------ dot sub-phases (all 8 waves, K-split) ------
  auto cell0_dot = [&](const float* s0hT) {
    float2 acc[8];
    #pragma unroll
    for (int c=0;c<8;c++) acc[c] = make_float2(0.f,0.f);
    dot_k8(s0hT + (size_t)(wv*64)*128, WT0 + (wv*64)*8, lane, 64, acc);
    #pragma unroll
    for (int c=0;c<8;c++) *(float2*)&part0[(wv*8+c)*128 + 2*lane] = acc[c];
  };
  auto att_dot = [&](const float* s0full) {
    float2 acc[2];
    acc[0]=make_float2(0.f,0.f); acc[1]=make_float2(0.f,0.f);
    dot_k2(s0full + (size_t)(wv*128)*128, WTA + (wv*128)*2, lane, 128, acc);
    *(float2*)&attpart[(wv*2+0)*128 + 2*lane] = acc[0];
    *(float2*)&attpart[(wv*2+1)*128 + 2*lane] = acc[1];
  };
  auto cell1_dot = [&](const float* s0T_, const float* attT_, const float* s1pT_) {
    float2 acc[8];
    #pragma unroll
    for (int c=0;c<8;c++) acc[c] = make_float2(0.f,0.f);
    // coldest segment first: s1p (written 1 phase ago, remote)
    dot_k8(s1pT_ + (size_t)(wv*64)*128, WT1 + (1024 + wv*64)*8, lane, 64, acc);
    dot_k8(attT_ + (size_t)(wv*64)*128, WT1 + (512  + wv*64)*8, lane, 64, acc);
    dot_k8(s0T_  + (size_t)(wv*64)*128, WT1 + (       wv*64)*8, lane, 64, acc);
    #pragma unroll
    for (int c=0;c<8;c++) *(float2*)&part1[(wv*8+c)*128 + 2*lane] = acc[c];
  };

  // ------ pointwise sub-phases (256 threads each; tid2 in [0,256)) ------
  auto cell0_point = [&](int u, const float* prevT, float* dstT, int tid2) {
    const int r = tid2 & 127, j = tid2 >> 7;
    const int nh = n0 + j;
    float g4[4];
    #pragma unroll
    for (int g=0; g<4; ++g) {
      float s = 0.f;
      #pragma unroll
      for (int ks=0; ks<8; ++ks) s += part0[(ks*8 + g*2 + j)*128 + r];
      g4[g] = s + X0GT[((size_t)u*NG + g*512 + nh)*128 + r];
    }
    const float c_old = prevT[(size_t)(512+nh)*128 + r];
    const float c_new = sigf(g4[1])*c_old + sigf(g4[0])*tanhf(g4[2]);
    const float h_new = sigf(g4[3])*tanhf(c_new);
    dstT[(size_t)nh*128 + r]       = h_new;
    dstT[(size_t)(512+nh)*128 + r] = c_new;
    if (u == S-1) { fin0[r*HB + nh] = h_new; fin0[r*HB + H + nh] = c_new; }
  };
  auto att_point = [&](float* attw, int tid2) {
    const int r = tid2 & 127, c = tid2 >> 7;
    float s = 0.f;
    #pragma unroll
    for (int ks=0; ks<8; ++ks) s += attpart[(ks*2 + c)*128 + r];
    attw[(size_t)(n0+c)*128 + r] = tanhf(s + batt[n0+c]);
  };
  auto cell1_point = [&](int t, const float* s1pT_, float* dstT, int tid2) {
    const int r = tid2 & 127, j = tid2 >> 7;
    const int nh = n0 + j;
    float g4[4];
    #pragma unroll
    for (int g=0; g<4; ++g) {
      float s = 0.f;
      #pragma unroll
      for (int ks=0; ks<8; ++ks) s += part1[(ks*8 + g*2 + j)*128 + r];
      g4[g] = s + b1[g*512 + nh];
    }
    const float c_old = s1pT_[(size_t)(512+nh)*128 + r];
    const float c_new = sigf(g4[1])*c_old + sigf(g4[0])*tanhf(g4[2]);
    const float h_new = sigf(g4[3])*tanhf(c_new);
    dstT[(size_t)nh*128 + r]       = h_new;
    dstT[(size_t)(512+nh)*128 + r] = c_new;
    H1T[((size_t)t*512 + nh)*128 + r] = h_new;
    if (t == S-1) { fin1[r*HB + nh] = h_new; fin1[r*HB + H + nh] = c_new; }
  };

  // ================= prologue =================
  // P0: cell0(0) from initT
  cell0_dot(initT);
  __syncthreads();
  if (tid < 256) cell0_point(0, initT, s0b[0], tid);
  grid.sync();

  // P1: att(0) + cell0(1), both from s0(0)
  att_dot(s0b[0]);
  cell0_dot(s0b[0]);
  __syncthreads();
  if (tid < 256) att_point(atb[0], tid);
  else           cell0_point(1, s0b[0], s0b[1], tid - 256);
  grid.sync();

  // ================= main pipeline: 1 sync per step =================
  for (int t = 0; t < S; ++t) {
    const float* s1pT_ = (t == 0) ? initT + 1024*128 : s1b[(t+1)&1];
    cell1_dot(s0b[t%3], atb[t&1], s1pT_);
    if (t+1 < S) {
      att_dot(s0b[(t+1)%3]);
      if (t+2 < S) cell0_dot(s0b[(t+1)%3]);
    }
    __syncthreads();
    if (tid < 256) {
      cell1_point(t, s1pT_, s1b[t&1], tid);
    } else {
      if (t+1 < S) att_point(atb[(t+1)&1], tid - 256);
      if (t+2 < S) cell0_point(t+2, s0b[(t+1)%3], s0b[(t+2)%3], tid - 256);
    }
    if (t < S-1) grid.sync();
  }
}

// ---------------------------------------------------------------------------
// K5: logits[b][t][:] = H1T-row @ W_out + b_out.  M=2560, N=10000, K=512.
// ---------------------------------------------------------------------------
__global__ __launch_bounds__(256) void k_logits(
    const float* __restrict__ H1T, const float* __restrict__ Wout,
    const float* __restrict__ bout, float* __restrict__ out)
{
  __shared__ __align__(16) float As[8][128];
  __shared__ __align__(16) float Bs[8][128];
  const int tid = threadIdx.x;
  const int m0 = blockIdx.y * 128, n0 = blockIdx.x * 128;
  const int tt = blockIdx.y;
  const int tx = tid & 15, ty = tid >> 4;

  const int akk = tid >> 5;
  const int ab4 = (tid & 31) * 4;
  const int bkk = tid >> 5;
  const int bc4 = (tid & 31) * 4;

  float acc[2][2][4][4];
  #pragma unroll
  for (int p=0;p<2;p++)
    #pragma unroll
    for (int q=0;q<2;q++)
      #pragma unroll
      for (int i=0;i<4;i++)
        #pragma unroll
        for (int j=0;j<4;j++) acc[p][q][i][j]=0.f;

  for (int kt = 0; kt < 512/8; ++kt) {
    float4 av = *(const float4*)(H1T + ((size_t)tt*512 + kt*8 + akk)*128 + ab4);
    const int bcol = n0 + bc4;
    float4 bv = make_float4(0.f,0.f,0.f,0.f);
    if (bcol < V) bv = *(const float4*)(Wout + (size_t)(kt*8 + bkk)*V + bcol);
    __syncthreads();
    *(float4*)&As[akk][ab4] = av;
    *(float4*)&Bs[bkk][bc4] = bv;
    __syncthreads();
    #pragma unroll
    for (int kk=0; kk<8; ++kk) {
      float a[2][4], b[2][4];
      *(float4*)a[0] = *(const float4*)&As[kk][ty*4];
      *(float4*)a[1] = *(const float4*)&As[kk][64 + ty*4];
      *(float4*)b[0] = *(const float4*)&Bs[kk][tx*4];
      *(float4*)b[1] = *(const float4*)&Bs[kk][64 + tx*4];
      #pragma unroll
      for (int p=0;p<2;p++)
        #pragma unroll
        for (int q=0;q<2;q++)
          #pragma unroll
          for (int i=0;i<4;i++)
            #pragma unroll
            for (int j=0;j<4;j++)
              acc[p][q][i][j] += a[p][i] * b[q][j];
    }
  }

  #pragma unroll
  for (int p=0;p<2;p++)
    #pragma unroll
    for (int i=0;i<4;i++) {
      const int row = m0 + p*64 + ty*4 + i;
      const int t_ = row >> 7, b_ = row & 127;
      float* orow = out + ((size_t)b_*S + t_) * V;
      #pragma unroll
      for (int q=0;q<2;q++) {
        const int col = n0 + q*64 + tx*4;
        if (col < V) {
          float4 bb = *(const float4*)(bout + col);
          float4 o;
          o.x = acc[p][q][i][0] + bb.x; o.y = acc[p][q][i][1] + bb.y;
          o.z = acc[p][q][i][2] + bb.z; o.w = acc[p][q][i][3] + bb.w;
          *(float4*)(orow + col) = o;
        }
      }
    }
}

// ---------------------------------------------------------------------------
extern "C" void kernel_launch(void* const* d_in, const int* in_sizes, int n_in,
                              void* d_out, int out_size, void* d_ws, size_t ws_size,
                              hipStream_t stream) {
  const int*   tok  = (const int*)  d_in[0];
  const float* base = (const float*)d_in[1];
  const float* init = (const float*)d_in[2];
  const float* emb  = (const float*)d_in[3];
  const float* W0   = (const float*)d_in[4];
  const float* b0   = (const float*)d_in[5];
  const float* W1   = (const float*)d_in[6];
  const float* b1   = (const float*)d_in[7];
  const float* Watt = (const float*)d_in[8];
  const float* batt = (const float*)d_in[9];
  const float* Wout = (const float*)d_in[10];
  const float* bout = (const float*)d_in[11];
  float* out = (float*)d_out;

  float* ws    = (float*)d_ws;
  float* X0GT  = ws;                          // 2560*2048 (transposed [t][n][b])
  float* s0b0  = X0GT + (size_t)2560*NG;      // 1024*128 x3
  float* s0b1  = s0b0 + 131072;
  float* s0b2  = s0b1 + 131072;
  float* s1b0  = s0b2 + 131072;               // 1024*128 x2
  float* s1b1  = s1b0 + 131072;
  float* at0   = s1b1 + 131072;               // 512*128 x2
  float* at1   = at0 + 65536;
  float* H1T   = at1 + 65536;                 // S*512*128
  float* initT = H1T + (size_t)S*512*128;     // 2*1024*128

  float* fin0 = out + (size_t)B*S*V;
  float* fin1 = fin0 + (size_t)B*HB;

  k_tr_init<<<256, 256, 0, stream>>>(init, initT);
  k_x0g<<<dim3(16,20),256,0,stream>>>(tok, base, emb, W0, b0, X0GT);

  const unsigned int REC_LDS = (4096 + 2048 + 12288 + 8192 + 8192 + 2048) * 4; // 147456 B
  hipFuncSetAttribute((const void*)k_rec,
                      hipFuncAttributeMaxDynamicSharedMemorySize, REC_LDS);
  void* args[] = { (void*)&initT, (void*)&W0, (void*)&Watt, (void*)&batt,
                   (void*)&W1, (void*)&b1, (void*)&X0GT,
                   (void*)&s0b0, (void*)&s0b1, (void*)&s0b2,
                   (void*)&s1b0, (void*)&s1b1, (void*)&at0, (void*)&at1,
                   (void*)&H1T, (void*)&fin0, (void*)&fin1 };
  hipLaunchCooperativeKernel((void*)k_rec, dim3(256), dim3(512),
                             args, REC_LDS, stream);

  k_logits<<<dim3(79,20),256,0,stream>>>(H1T, Wout, bout, out);
}